// Round 10
// baseline (48.393 us; speedup 1.0000x reference)
//
#include <hip/hip_runtime.h>

#define E10 10

// ---------- Kernel 1: Spart partials (r4-proven) + psum/cnt init ----------
__global__ __launch_bounds__(256) void k_wsum(const float* __restrict__ W,
                                              const float* __restrict__ eww,
                                              const float* __restrict__ ewb,
                                              float* __restrict__ Spart,
                                              float* __restrict__ psum,
                                              unsigned* __restrict__ cnt) {
    const int t  = threadIdx.x;
    const int jt = blockIdx.x;   // 0..31
    const int ic = blockIdx.y;   // 0..7
    const int b  = blockIdx.z;   // 0..7
    if (jt == 0 && ic == 0 && b == 0) {   // init for iter2's election
        if (t < 8) cnt[t] = 0u;
        else if (t < 88) psum[t - 8] = 0.f;
    }
    const int cp = t & 15;       // col pair
    const int rg = t >> 4;       // row group (16 x 8 rows)
    const int j0 = jt * 32 + cp * 2;
    const int i0 = ic * 128 + rg * 8;

    float cw[E10], cb[E10];
#pragma unroll
    for (int e = 0; e < E10; e++) { cw[e] = eww[e]; cb[e] = ewb[e]; }

    float a0[E10], a1[E10];
#pragma unroll
    for (int e = 0; e < E10; e++) { a0[e] = 0.f; a1[e] = 0.f; }

    const float* Wp = W + ((size_t)(b * 1024 + i0) << 10) + j0;
#pragma unroll
    for (int r = 0; r < 8; r++) {
        const float2 w = *(const float2*)(Wp + ((size_t)r << 10));
#pragma unroll
        for (int e = 0; e < E10; e++) {
            a0[e] += fmaxf(w.x * cw[e] + cb[e], 0.f);
            a1[e] += fmaxf(w.y * cw[e] + cb[e], 0.f);
        }
    }

    __shared__ float smf[16][32][E10];   // 20 KB
#pragma unroll
    for (int e = 0; e < E10; e++) {
        smf[rg][cp * 2][e]     = a0[e];
        smf[rg][cp * 2 + 1][e] = a1[e];
    }
    __syncthreads();
    if (t < 32) {
        float S[E10];
#pragma unroll
        for (int e = 0; e < E10; e++) S[e] = smf[0][t][e];
#pragma unroll
        for (int r = 1; r < 16; r++)
#pragma unroll
            for (int e = 0; e < E10; e++) S[e] += smf[r][t][e];
        float2* Sp = (float2*)(Spart + ((size_t)(ic * 8192 + b * 1024 + jt * 32 + t)) * E10);
#pragma unroll
        for (int q = 0; q < 5; q++) Sp[q] = make_float2(S[2 * q], S[2 * q + 1]);
    }
}

// ---------- Kernel 2: merge 8 chunks; base; emb1 (r4-proven verbatim) ----------
__global__ __launch_bounds__(256) void k_base(const float* __restrict__ Spart,
                                              const float* __restrict__ feat,
                                              const float* __restrict__ selw,
                                              const float* __restrict__ selb,
                                              const float* __restrict__ nbww,
                                              const float* __restrict__ nbwb,
                                              const float* __restrict__ nbpb,
                                              float* __restrict__ base,
                                              float* __restrict__ embA) {
    const int t = threadIdx.x;
    const int g = t & 31;
    const int m = t >> 5;                 // 0..7
    const int node = blockIdx.x * 32 + g; // 0..8191

    float S[E10];
    const float2* p = (const float2*)(Spart + ((size_t)(m * 8192 + node)) * E10);
#pragma unroll
    for (int q = 0; q < 5; q++) {
        const float2 v = p[q];
        S[2 * q] = v.x;
        S[2 * q + 1] = v.y;
    }

    __shared__ float lds[8][32][E10];
#pragma unroll
    for (int e = 0; e < E10; e++) lds[m][g][e] = S[e];
    __syncthreads();
    if (m == 0) {
#pragma unroll
        for (int mm = 1; mm < 8; mm++)
#pragma unroll
            for (int e = 0; e < E10; e++) S[e] += lds[mm][g][e];
        const float f = feat[node];
#pragma unroll
        for (int o = 0; o < E10; o++) {
            float vw = nbwb[o];
#pragma unroll
            for (int e = 0; e < E10; e++) vw += S[e] * nbww[o * E10 + e];
            const float bv = f * selw[o] + selb[o] + vw;
            base[(size_t)node * E10 + o] = bv;
            embA[(size_t)node * E10 + o] = fmaxf(bv + nbpb[o], 0.f);
        }
    }
}

// ---------- Kernel 3/4: r4-proven iter core; FINAL fuses readout (r7-proven tail)
// grid (32 rowchunk, 8 b), 256 thr. Wave: 8 rows = 4 groups x 2 rows; 16-lane
// j-split x 4 js; each LDS b128 pair feeds both rows of the group.
template<int FINAL>
__global__ __launch_bounds__(256) void k_iterX(
    const float* __restrict__ A,
    const float* __restrict__ embIn,
    const float* __restrict__ base,
    const float* __restrict__ nbpw, const float* __restrict__ nbpb,
    float* __restrict__ embOut,
    float* __restrict__ out,
    float* __restrict__ psum, unsigned* __restrict__ cnt,
    const float* __restrict__ qallw, const float* __restrict__ qallb,
    const float* __restrict__ qredw, const float* __restrict__ qredb,
    const float* __restrict__ qactw, const float* __restrict__ qactb)
{
    __shared__ __align__(16) float2 l2[5 * 1024];   // [e2][j], 40 KB
    const int t    = threadIdx.x;
    const int b    = blockIdx.y;
    const int lane = t & 63;
    const int wave = t >> 6;
    const int lg   = lane >> 4;   // row-pair group 0..3
    const int ll   = lane & 15;   // j lane

    const float2* src = (const float2*)(embIn + (size_t)b * 10240);
    for (int jj = t; jj < 1024; jj += 256) {
#pragma unroll
        for (int e2 = 0; e2 < 5; e2++) l2[e2 * 1024 + jj] = src[jj * 5 + e2];
    }

    const int o = (ll < E10) ? ll : 0;
    float nw[E10];
    const float pb = nbpb[o];
#pragma unroll
    for (int e = 0; e < E10; e++) nw[e] = nbpw[o * E10 + e];

    float K2c = 0.f, c2 = 0.f;
    if (FINAL) {
#pragma unroll
        for (int oo = 0; oo < E10; oo++) {
            K2c += qredw[E10 + oo] * qactw[oo * E10 + o];
            c2  += qredw[E10 + oo] * qactb[oo];
        }
        c2 += qredb[0];
        if (ll >= E10) K2c = 0.f;
    }
    __syncthreads();

    const int rowA = blockIdx.x * 32 + wave * 8 + lg * 2;
    const float* ArA = A + (((size_t)b << 10) + rowA << 10);
    const float* ArB = ArA + 1024;

    float accA[E10], accB[E10];
#pragma unroll
    for (int e = 0; e < E10; e++) { accA[e] = 0.f; accB[e] = 0.f; }

    float4 a4A = *(const float4*)(ArA + ll * 4);
    float4 a4B = *(const float4*)(ArB + ll * 4);
#pragma unroll
    for (int k = 0; k < 16; k++) {
        const int j0 = ll * 4 + k * 64;
        float4 nA, nB;
        if (k < 15) {
            nA = *(const float4*)(ArA + j0 + 64);
            nB = *(const float4*)(ArB + j0 + 64);
        }
#pragma unroll
        for (int e2 = 0; e2 < 5; e2++) {
            const float4* lp = (const float4*)&l2[e2 * 1024 + j0];
            const float4 qa = lp[0];
            const float4 qb = lp[1];
            accA[2 * e2]     += a4A.x * qa.x + a4A.y * qa.z + a4A.z * qb.x + a4A.w * qb.z;
            accA[2 * e2 + 1] += a4A.x * qa.y + a4A.y * qa.w + a4A.z * qb.y + a4A.w * qb.w;
            accB[2 * e2]     += a4B.x * qa.x + a4B.y * qa.z + a4B.z * qb.x + a4B.w * qb.z;
            accB[2 * e2 + 1] += a4B.x * qa.y + a4B.y * qa.w + a4B.z * qb.y + a4B.w * qb.w;
        }
        if (k < 15) { a4A = nA; a4B = nB; }
    }

#pragma unroll
    for (int e = 0; e < E10; e++) {
        float v = accA[e];
        v += __shfl_xor(v, 8);
        v += __shfl_xor(v, 4);
        v += __shfl_xor(v, 2);
        v += __shfl_xor(v, 1);
        accA[e] = v;
        float w = accB[e];
        w += __shfl_xor(w, 8);
        w += __shfl_xor(w, 4);
        w += __shfl_xor(w, 2);
        w += __shfl_xor(w, 1);
        accB[e] = w;
    }

    const size_t offA = ((size_t)b * 1024 + rowA) * E10 + o;
    float vA = 0.f, vB = 0.f;
    if (ll < E10) {
        float pA = pb, pB = pb;
#pragma unroll
        for (int e = 0; e < E10; e++) {
            pA += accA[e] * nw[e];
            pB += accB[e] * nw[e];
        }
        vA = fmaxf(base[offA] + pA, 0.f);
        vB = fmaxf(base[offA + E10] + pB, 0.f);
        if (!FINAL) {
            embOut[offA]       = vA;
            embOut[offA + E10] = vB;
        } else {
            out[8192 + offA]       = vA;
            out[8192 + offA + E10] = vB;
        }
    }
    if (!FINAL) return;

    // ---- FINAL readout tail (r7-proven election, 256-thr pair layout) ----
    // per-node q partial: reduce v[e]*K2c[e] over the 16-lane group
    float pdA = vA * K2c, pdB = vB * K2c;
    pdA += __shfl_xor(pdA, 8);
    pdA += __shfl_xor(pdA, 4);
    pdA += __shfl_xor(pdA, 2);
    pdA += __shfl_xor(pdA, 1);
    pdB += __shfl_xor(pdB, 8);
    pdB += __shfl_xor(pdB, 4);
    pdB += __shfl_xor(pdB, 2);
    pdB += __shfl_xor(pdB, 1);
    if (ll == 0) {
        out[b * 1024 + rowA]     = c2 + pdA;
        out[b * 1024 + rowA + 1] = c2 + pdB;
    }
    // psum: channel ll over this wave's 8 rows
    float vs = vA + vB;
    vs += __shfl_xor(vs, 16);
    vs += __shfl_xor(vs, 32);

    __shared__ float sps[E10];
    if (t < E10) sps[t] = 0.f;
    __syncthreads();
    if (lane < E10) atomicAdd(&sps[lane], vs);
    __syncthreads();
    if (t < E10) atomicAdd(psum + b * E10 + t, sps[t]);
    __syncthreads();

    __shared__ unsigned eflag;
    __shared__ float s_sdot;
    if (t == 0) {
        __threadfence();                              // release (L2 wb)
        const unsigned old = atomicAdd(cnt + b, 1u);
        eflag = (old == 31u) ? 1u : 0u;
    }
    __syncthreads();
    if (eflag) {
        if (t == 0) {
            __threadfence();                          // acquire (cache inv)
            float sd = 0.f;
#pragma unroll
            for (int oo = 0; oo < E10; oo++) {
                float se = qallb[oo];
#pragma unroll
                for (int e = 0; e < E10; e++)
                    se += psum[b * E10 + e] * qallw[oo * E10 + e];
                sd += se * qredw[oo];
            }
            s_sdot = sd;
        }
        __syncthreads();
        const float sd = s_sdot;
        out[b * 1024 + t]       += sd;
        out[b * 1024 + 256 + t] += sd;
        out[b * 1024 + 512 + t] += sd;
        out[b * 1024 + 768 + t] += sd;
    }
}

extern "C" void kernel_launch(void* const* d_in, const int* in_sizes, int n_in,
                              void* d_out, int out_size, void* d_ws, size_t ws_size,
                              hipStream_t stream) {
    (void)in_sizes; (void)n_in; (void)out_size; (void)ws_size;
    const float* features  = (const float*)d_in[0];
    const float* weights   = (const float*)d_in[1];
    const float* adjacency = (const float*)d_in[2];
    const float* sel_w     = (const float*)d_in[3];
    const float* sel_b     = (const float*)d_in[4];
    const float* nbp_w     = (const float*)d_in[5];
    const float* nbp_b     = (const float*)d_in[6];
    const float* nbw_w     = (const float*)d_in[7];
    const float* nbw_b     = (const float*)d_in[8];
    const float* nbwew_w   = (const float*)d_in[9];
    const float* nbwew_b   = (const float*)d_in[10];
    const float* qred_w    = (const float*)d_in[11];
    const float* qred_b    = (const float*)d_in[12];
    const float* qall_w    = (const float*)d_in[13];
    const float* qall_b    = (const float*)d_in[14];
    const float* qact_w    = (const float*)d_in[15];
    const float* qact_b    = (const float*)d_in[16];
    float* out = (float*)d_out;
    float* ws  = (float*)d_ws;

    float* Spart = ws;                       // 655360
    float* base  = ws + 655360;              // 81920
    float* embA  = base + 81920;             // 81920
    float* embB  = embA + 81920;             // 81920
    float* psum  = embB + 81920;             // 80
    unsigned* cnt = (unsigned*)(psum + 80);  // 8

    k_wsum<<<dim3(32, 8, 8), 256, 0, stream>>>(weights, nbwew_w, nbwew_b, Spart,
                                               psum, cnt);
    k_base<<<256, 256, 0, stream>>>(Spart, features, sel_w, sel_b, nbw_w, nbw_b,
                                    nbp_b, base, embA);
    k_iterX<0><<<dim3(32, 8), 256, 0, stream>>>(
        adjacency, embA, base, nbp_w, nbp_b, embB, out, psum, cnt,
        qall_w, qall_b, qred_w, qred_b, qact_w, qact_b);
    k_iterX<1><<<dim3(32, 8), 256, 0, stream>>>(
        adjacency, embB, base, nbp_w, nbp_b, embA, out, psum, cnt,
        qall_w, qall_b, qred_w, qred_b, qact_w, qact_b);
}

// Round 11
// 44.775 us; speedup vs baseline: 1.0808x; 1.0808x over previous
//
#include <hip/hip_runtime.h>

#define E10 10

// ---------- Kernel 1: Spart[ic][node][e] = sum over 128 rows of relu(W*cw+cb)
// grid (32 jt, 8 ic, 8 b) = 2048 blocks, 256 thr. thread = 8 rows x 2 cols.
__global__ __launch_bounds__(256) void k_wsum(const float* __restrict__ W,
                                              const float* __restrict__ eww,
                                              const float* __restrict__ ewb,
                                              float* __restrict__ Spart) {
    const int t  = threadIdx.x;
    const int jt = blockIdx.x;   // 0..31
    const int ic = blockIdx.y;   // 0..7
    const int b  = blockIdx.z;   // 0..7
    const int cp = t & 15;       // col pair
    const int rg = t >> 4;       // row group (16 x 8 rows)
    const int j0 = jt * 32 + cp * 2;
    const int i0 = ic * 128 + rg * 8;

    float cw[E10], cb[E10];
#pragma unroll
    for (int e = 0; e < E10; e++) { cw[e] = eww[e]; cb[e] = ewb[e]; }

    float a0[E10], a1[E10];
#pragma unroll
    for (int e = 0; e < E10; e++) { a0[e] = 0.f; a1[e] = 0.f; }

    const float* Wp = W + ((size_t)(b * 1024 + i0) << 10) + j0;
#pragma unroll
    for (int r = 0; r < 8; r++) {
        const float2 w = *(const float2*)(Wp + ((size_t)r << 10));
#pragma unroll
        for (int e = 0; e < E10; e++) {
            a0[e] += fmaxf(w.x * cw[e] + cb[e], 0.f);
            a1[e] += fmaxf(w.y * cw[e] + cb[e], 0.f);
        }
    }

    __shared__ float smf[16][32][E10];   // 20 KB
#pragma unroll
    for (int e = 0; e < E10; e++) {
        smf[rg][cp * 2][e]     = a0[e];
        smf[rg][cp * 2 + 1][e] = a1[e];
    }
    __syncthreads();
    if (t < 32) {
        float S[E10];
#pragma unroll
        for (int e = 0; e < E10; e++) S[e] = smf[0][t][e];
#pragma unroll
        for (int r = 1; r < 16; r++)
#pragma unroll
            for (int e = 0; e < E10; e++) S[e] += smf[r][t][e];
        float2* Sp = (float2*)(Spart + ((size_t)(ic * 8192 + b * 1024 + jt * 32 + t)) * E10);
#pragma unroll
        for (int q = 0; q < 5; q++) Sp[q] = make_float2(S[2 * q], S[2 * q + 1]);
    }
}

// ---------- Kernel 2: merge 8 chunks; base = v_sel + v_weights; emb1
// grid 256 x 256. g = t&31 node, m = t>>5 chunk.
__global__ __launch_bounds__(256) void k_base(const float* __restrict__ Spart,
                                              const float* __restrict__ feat,
                                              const float* __restrict__ selw,
                                              const float* __restrict__ selb,
                                              const float* __restrict__ nbww,
                                              const float* __restrict__ nbwb,
                                              const float* __restrict__ nbpb,
                                              float* __restrict__ base,
                                              float* __restrict__ embA) {
    const int t = threadIdx.x;
    const int g = t & 31;
    const int m = t >> 5;                 // 0..7
    const int node = blockIdx.x * 32 + g; // 0..8191

    float S[E10];
    const float2* p = (const float2*)(Spart + ((size_t)(m * 8192 + node)) * E10);
#pragma unroll
    for (int q = 0; q < 5; q++) {
        const float2 v = p[q];
        S[2 * q] = v.x;
        S[2 * q + 1] = v.y;
    }

    __shared__ float lds[8][32][E10];
#pragma unroll
    for (int e = 0; e < E10; e++) lds[m][g][e] = S[e];
    __syncthreads();
    if (m == 0) {
#pragma unroll
        for (int mm = 1; mm < 8; mm++)
#pragma unroll
            for (int e = 0; e < E10; e++) S[e] += lds[mm][g][e];
        const float f = feat[node];
#pragma unroll
        for (int o = 0; o < E10; o++) {
            float vw = nbwb[o];
#pragma unroll
            for (int e = 0; e < E10; e++) vw += S[e] * nbww[o * E10 + e];
            const float bv = f * selw[o] + selb[o] + vw;
            base[(size_t)node * E10 + o] = bv;
            embA[(size_t)node * E10 + o] = fmaxf(bv + nbpb[o], 0.f);
        }
    }
}

// ---------- Kernel 3: embOut = relu(base + nbp(A @ embIn))
// grid (32 rowchunk, 8 b), 256 thr. Wave: 8 rows = 4 groups x 2 rows; 16-lane
// j-split x 4 js; each LDS b128 pair feeds both rows of the group.
__global__ __launch_bounds__(256) void k_iter(const float* __restrict__ A,
                                              const float* __restrict__ embIn,
                                              const float* __restrict__ base,
                                              const float* __restrict__ nbpw,
                                              const float* __restrict__ nbpb,
                                              float* __restrict__ embOut) {
    __shared__ __align__(16) float2 l2[5 * 1024];   // [e2][j], 40 KB
    const int t    = threadIdx.x;
    const int b    = blockIdx.y;
    const int lane = t & 63;
    const int wave = t >> 6;
    const int lg   = lane >> 4;   // row-pair group 0..3
    const int ll   = lane & 15;   // j lane

    const float2* src = (const float2*)(embIn + (size_t)b * 10240);
    for (int jj = t; jj < 1024; jj += 256) {
#pragma unroll
        for (int e2 = 0; e2 < 5; e2++) l2[e2 * 1024 + jj] = src[jj * 5 + e2];
    }

    const int o = (ll < E10) ? ll : 0;
    float nw[E10];
    const float pb = nbpb[o];
#pragma unroll
    for (int e = 0; e < E10; e++) nw[e] = nbpw[o * E10 + e];
    __syncthreads();

    const int rowA = blockIdx.x * 32 + wave * 8 + lg * 2;
    const float* ArA = A + (((size_t)b << 10) + rowA << 10);
    const float* ArB = ArA + 1024;

    float accA[E10], accB[E10];
#pragma unroll
    for (int e = 0; e < E10; e++) { accA[e] = 0.f; accB[e] = 0.f; }

    float4 a4A = *(const float4*)(ArA + ll * 4);
    float4 a4B = *(const float4*)(ArB + ll * 4);
#pragma unroll
    for (int k = 0; k < 16; k++) {
        const int j0 = ll * 4 + k * 64;
        float4 nA, nB;
        if (k < 15) {
            nA = *(const float4*)(ArA + j0 + 64);
            nB = *(const float4*)(ArB + j0 + 64);
        }
#pragma unroll
        for (int e2 = 0; e2 < 5; e2++) {
            const float4* lp = (const float4*)&l2[e2 * 1024 + j0];
            const float4 qa = lp[0];   // j0,j0+1 (e 2e2, 2e2+1)
            const float4 qb = lp[1];   // j0+2,j0+3
            accA[2 * e2]     += a4A.x * qa.x + a4A.y * qa.z + a4A.z * qb.x + a4A.w * qb.z;
            accA[2 * e2 + 1] += a4A.x * qa.y + a4A.y * qa.w + a4A.z * qb.y + a4A.w * qb.w;
            accB[2 * e2]     += a4B.x * qa.x + a4B.y * qa.z + a4B.z * qb.x + a4B.w * qb.z;
            accB[2 * e2 + 1] += a4B.x * qa.y + a4B.y * qa.w + a4B.z * qb.y + a4B.w * qb.w;
        }
        if (k < 15) { a4A = nA; a4B = nB; }
    }

#pragma unroll
    for (int e = 0; e < E10; e++) {
        float v = accA[e];
        v += __shfl_xor(v, 8);
        v += __shfl_xor(v, 4);
        v += __shfl_xor(v, 2);
        v += __shfl_xor(v, 1);
        accA[e] = v;
        float w = accB[e];
        w += __shfl_xor(w, 8);
        w += __shfl_xor(w, 4);
        w += __shfl_xor(w, 2);
        w += __shfl_xor(w, 1);
        accB[e] = w;
    }

    if (ll < E10) {
        float pA = pb, pB = pb;
#pragma unroll
        for (int e = 0; e < E10; e++) {
            pA += accA[e] * nw[e];
            pB += accB[e] * nw[e];
        }
        const size_t offA = ((size_t)b * 1024 + rowA) * E10 + o;
        embOut[offA]       = fmaxf(base[offA] + pA, 0.f);
        embOut[offA + E10] = fmaxf(base[offA + E10] + pB, 0.f);
    }
}

// ---------- Kernel 4: global readout + q_vals + emb copy
// grid 32 (4 per b), 256 thr. Each block redundantly reduces its b, then
// outputs its quarter of the nodes.
__global__ __launch_bounds__(256) void k_final(const float* __restrict__ emb,
                                               const float* __restrict__ qallw,
                                               const float* __restrict__ qallb,
                                               const float* __restrict__ qredw,
                                               const float* __restrict__ qredb,
                                               const float* __restrict__ qactw,
                                               const float* __restrict__ qactb,
                                               float* __restrict__ out) {
    const int t = threadIdx.x;
    const int b = blockIdx.x >> 2;
    const int qt = blockIdx.x & 3;
    const int lane = t & 63, wave = t >> 6;

    float S[E10];
#pragma unroll
    for (int e = 0; e < E10; e++) S[e] = 0.f;
    for (int n = t; n < 1024; n += 256) {
        const float2* p = (const float2*)(emb + ((size_t)b * 1024 + n) * E10);
#pragma unroll
        for (int q = 0; q < 5; q++) {
            const float2 v = p[q];
            S[2 * q] += v.x;
            S[2 * q + 1] += v.y;
        }
    }
#pragma unroll
    for (int e = 0; e < E10; e++) {
        float v = S[e];
        v += __shfl_xor(v, 32);
        v += __shfl_xor(v, 16);
        v += __shfl_xor(v, 8);
        v += __shfl_xor(v, 4);
        v += __shfl_xor(v, 2);
        v += __shfl_xor(v, 1);
        S[e] = v;
    }
    __shared__ float lds[4][E10];
    __shared__ float sdot_s;
    if (lane == 0) {
#pragma unroll
        for (int e = 0; e < E10; e++) lds[wave][e] = S[e];
    }
    __syncthreads();
    if (t == 0) {
        float Sf[E10];
#pragma unroll
        for (int e = 0; e < E10; e++)
            Sf[e] = lds[0][e] + lds[1][e] + lds[2][e] + lds[3][e];
        float sd = 0.f;
#pragma unroll
        for (int o = 0; o < E10; o++) {
            float se = qallb[o];
#pragma unroll
            for (int e = 0; e < E10; e++) se += Sf[e] * qallw[o * E10 + e];
            sd += se * qredw[o];
        }
        sdot_s = sd;
    }
    __syncthreads();

    const int node = b * 1024 + qt * 256 + t;
    float v[E10];
    const float2* p = (const float2*)(emb + (size_t)node * E10);
#pragma unroll
    for (int q = 0; q < 5; q++) {
        const float2 w = p[q];
        v[2 * q] = w.x;
        v[2 * q + 1] = w.y;
    }
    float qv = qredb[0] + sdot_s;
#pragma unroll
    for (int o = 0; o < E10; o++) {
        float pa = qactb[o];
#pragma unroll
        for (int e = 0; e < E10; e++) pa += v[e] * qactw[o * E10 + e];
        qv += pa * qredw[E10 + o];
    }
    out[node] = qv;
    float2* o2 = (float2*)(out + 8192 + (size_t)node * E10);
#pragma unroll
    for (int q = 0; q < 5; q++) o2[q] = make_float2(v[2 * q], v[2 * q + 1]);
}

extern "C" void kernel_launch(void* const* d_in, const int* in_sizes, int n_in,
                              void* d_out, int out_size, void* d_ws, size_t ws_size,
                              hipStream_t stream) {
    (void)in_sizes; (void)n_in; (void)out_size; (void)ws_size;
    const float* features  = (const float*)d_in[0];
    const float* weights   = (const float*)d_in[1];
    const float* adjacency = (const float*)d_in[2];
    const float* sel_w     = (const float*)d_in[3];
    const float* sel_b     = (const float*)d_in[4];
    const float* nbp_w     = (const float*)d_in[5];
    const float* nbp_b     = (const float*)d_in[6];
    const float* nbw_w     = (const float*)d_in[7];
    const float* nbw_b     = (const float*)d_in[8];
    const float* nbwew_w   = (const float*)d_in[9];
    const float* nbwew_b   = (const float*)d_in[10];
    const float* qred_w    = (const float*)d_in[11];
    const float* qred_b    = (const float*)d_in[12];
    const float* qall_w    = (const float*)d_in[13];
    const float* qall_b    = (const float*)d_in[14];
    const float* qact_w    = (const float*)d_in[15];
    const float* qact_b    = (const float*)d_in[16];
    float* out = (float*)d_out;
    float* ws  = (float*)d_ws;

    float* Spart = ws;                       // 8*8192*10 = 655360 floats
    float* base  = ws + 655360;              // 81920
    float* embA  = base + 81920;             // 81920
    float* embB  = embA + 81920;             // 81920

    k_wsum<<<dim3(32, 8, 8), 256, 0, stream>>>(weights, nbwew_w, nbwew_b, Spart);
    k_base<<<256, 256, 0, stream>>>(Spart, features, sel_w, sel_b, nbw_w, nbw_b, nbp_b,
                                    base, embA);
    k_iter<<<dim3(32, 8), 256, 0, stream>>>(adjacency, embA, base, nbp_w, nbp_b, embB);
    k_iter<<<dim3(32, 8), 256, 0, stream>>>(adjacency, embB, base, nbp_w, nbp_b, embA);
    k_final<<<32, 256, 0, stream>>>(embA, qall_w, qall_b, qred_w, qred_b,
                                    qact_w, qact_b, out);
}